// Round 1
// 454.908 us; speedup vs baseline: 1.0065x; 1.0065x over previous
//
#include <hip/hip_runtime.h>

#define B 64
#define N 1025
#define C 768
#define H 12
#define HD 64
#define NT 17   // 64-row score tiles per batch

__device__ __forceinline__ float wave_reduce_add(float v) {
    #pragma unroll
    for (int m = 1; m < 64; m <<= 1) v += __shfl_xor(v, m, 64);
    return v;
}

// ---------------------------------------------------------------------------
// k_qproj: q[b][c] = 0.125 * (cls[b] . qW[c,:] + qb[c])
// grid (16 btiles, 48 ctiles of 16), block 256 (4 waves). Wave w = batch.
// ---------------------------------------------------------------------------
__global__ __launch_bounds__(256) void k_qproj(const float* __restrict__ x,
                                               const float* __restrict__ qW,
                                               const float* __restrict__ qb,
                                               float* __restrict__ qout) {
    __shared__ float cls[4 * C];
    int bt = blockIdx.x, ct = blockIdx.y, tid = threadIdx.x;
    for (int i = tid; i < 768; i += 256) {   // 768 float4 = 4 rows x 192
        int bl = i / 192, c4 = i % 192;
        ((float4*)cls)[i] = ((const float4*)(x + (size_t)(bt * 4 + bl) * N * C))[c4];
    }
    __syncthreads();
    int w = tid >> 6, lane = tid & 63;
    int b = bt * 4 + w;
    const float* clsrow = &cls[w * C];
    for (int cl = 0; cl < 16; ++cl) {
        int c = ct * 16 + cl;
        const float4* wr = (const float4*)(qW + (size_t)c * C + lane * 12);
        const float4* xr = (const float4*)(clsrow + lane * 12);
        float acc = 0.f;
        #pragma unroll
        for (int s = 0; s < 3; ++s) {
            float4 a = wr[s], v = xr[s];
            acc += a.x * v.x + a.y * v.y + a.z * v.z + a.w * v.w;
        }
        acc = wave_reduce_add(acc);
        if (lane == 0) qout[b * C + c] = 0.125f * (acc + qb[c]);
    }
}

// ---------------------------------------------------------------------------
// k_qk: qk[b][h][c'] = sum_{i<64} q[b][h*64+i] * kW[h*64+i][c']
//       qkb[b][h]    = sum_{i<64} q[b][h*64+i] * kb[h*64+i]
// grid (16 btiles, 12 heads), block 256.
// ---------------------------------------------------------------------------
__global__ __launch_bounds__(256) void k_qk(const float* __restrict__ q,
                                            const float* __restrict__ kW,
                                            const float* __restrict__ kb,
                                            float* __restrict__ qk,
                                            float* __restrict__ qkb) {
    int bt = blockIdx.x, h = blockIdx.y, tid = threadIdx.x;
    if (tid < 192) {
        float4 acc[4] = {};
        #pragma unroll 4
        for (int i = 0; i < HD; ++i) {
            int row = h * HD + i;
            float4 kv = *(const float4*)(kW + (size_t)row * C + tid * 4);
            #pragma unroll
            for (int bl = 0; bl < 4; ++bl) {
                float qv = q[(bt * 4 + bl) * C + row];  // uniform -> s_load
                acc[bl].x += qv * kv.x; acc[bl].y += qv * kv.y;
                acc[bl].z += qv * kv.z; acc[bl].w += qv * kv.w;
            }
        }
        #pragma unroll
        for (int bl = 0; bl < 4; ++bl) {
            int b = bt * 4 + bl;
            *(float4*)(qk + ((size_t)b * H + h) * C + tid * 4) = acc[bl];
        }
    }
    int w = tid >> 6, lane = tid & 63;
    int b = bt * 4 + w;
    float v = q[b * C + h * HD + lane] * kb[h * HD + lane];
    v = wave_reduce_add(v);
    if (lane == 0) qkb[b * H + h] = v;
}

// ---------------------------------------------------------------------------
// k_scores (FUSED with mix1): per (tile of 64 rows, b):
//   raw[h][n] = x[b,n,:] . qk[b,h,:]
//   s = raw + qkb;  a1 = s + w1W@s + w1b     (talking-heads pre-softmax)
//   writes a1 to sc in [b][n][12] coalesced layout,
//   emits per-tile per-head max and sum(exp(a1-max)).
// grid (17, 64), block 256. qk[b] in LDS (36 KB), reused as a1 tile buffer.
// ---------------------------------------------------------------------------
__global__ __launch_bounds__(256) void k_scores(const float* __restrict__ x,
                                                const float* __restrict__ qk,
                                                const float* __restrict__ qkbias,
                                                const float* __restrict__ w1W,
                                                const float* __restrict__ w1b,
                                                float* __restrict__ sc,
                                                float* __restrict__ mstat,
                                                float* __restrict__ sstat) {
    __shared__ float qs[12 * C];   // 36 KB; phase B reuses as a_lds[64][12]
    __shared__ float w1s[144], w1bs[12], qbs[12];
    int tile = blockIdx.x, b = blockIdx.y, tid = threadIdx.x;
    const float4* qksrc = (const float4*)(qk + (size_t)b * H * C);
    for (int i = tid; i < 2304; i += 256) ((float4*)qs)[i] = qksrc[i];
    if (tid < 144) w1s[tid] = w1W[tid];
    if (tid < 12)  { w1bs[tid] = w1b[tid]; qbs[tid] = qkbias[b * 12 + tid]; }
    __syncthreads();
    int w = tid >> 6, lane = tid & 63;
    int c16 = lane & 15, r = lane >> 4;
    int rowbase = tile * 64 + w * 16 + r * 4;
    const float* xb = x + (size_t)b * N * C;
    float acc[4][12] = {};
    for (int cc = 0; cc < C; cc += 128) {
        int c0 = cc + c16 * 4, c1 = c0 + 64;
        float4 xv0[4], xv1[4];
        #pragma unroll
        for (int j = 0; j < 4; ++j) {
            int row = rowbase + j;
            const float* xr = xb + (size_t)row * C;
            xv0[j] = (row < N) ? *(const float4*)(xr + c0) : make_float4(0.f,0.f,0.f,0.f);
            xv1[j] = (row < N) ? *(const float4*)(xr + c1) : make_float4(0.f,0.f,0.f,0.f);
        }
        #pragma unroll
        for (int h = 0; h < 12; ++h) {
            float4 q0 = *(const float4*)(qs + h * C + c0);
            float4 q1 = *(const float4*)(qs + h * C + c1);
            #pragma unroll
            for (int j = 0; j < 4; ++j) {
                acc[j][h] += xv0[j].x * q0.x + xv0[j].y * q0.y +
                             xv0[j].z * q0.z + xv0[j].w * q0.w;
                acc[j][h] += xv1[j].x * q1.x + xv1[j].y * q1.y +
                             xv1[j].z * q1.z + xv1[j].w * q1.w;
            }
        }
    }
    #pragma unroll
    for (int j = 0; j < 4; ++j)
        #pragma unroll
        for (int h = 0; h < 12; ++h) {
            float v = acc[j][h];
            v += __shfl_xor(v, 1); v += __shfl_xor(v, 2);
            v += __shfl_xor(v, 4); v += __shfl_xor(v, 8);
            acc[j][h] = v;
        }
    __syncthreads();             // all qs (qk) reads complete -> safe to reuse
    if (c16 == 0) {
        #pragma unroll
        for (int j = 0; j < 4; ++j)
            #pragma unroll
            for (int h = 0; h < 12; ++h)
                qs[(w * 16 + r * 4 + j) * 12 + h] = acc[j][h];
    }
    __syncthreads();
    if (tid < 64) {              // wave 0: mix1 + stats for the 64-row tile
        int row = tile * 64 + tid;
        bool valid = row < N;
        float s_[12], o[12];
        #pragma unroll
        for (int h = 0; h < 12; ++h) s_[h] = qs[tid * 12 + h] + qbs[h];
        #pragma unroll
        for (int g = 0; g < 12; ++g) {
            float a = s_[g] + w1bs[g];
            #pragma unroll
            for (int h = 0; h < 12; ++h) a += w1s[g * 12 + h] * s_[h];
            o[g] = a;
        }
        if (valid) {
            float* sp = sc + ((size_t)b * N + row) * 12;
            *(float4*)(sp)     = make_float4(o[0], o[1], o[2],  o[3]);
            *(float4*)(sp + 4) = make_float4(o[4], o[5], o[6],  o[7]);
            *(float4*)(sp + 8) = make_float4(o[8], o[9], o[10], o[11]);
        }
        #pragma unroll
        for (int g = 0; g < 12; ++g) {
            float mv = valid ? o[g] : -3e38f;
            #pragma unroll
            for (int m = 1; m < 64; m <<= 1) mv = fmaxf(mv, __shfl_xor(mv, m, 64));
            float e = valid ? __expf(o[g] - mv) : 0.f;
            e = wave_reduce_add(e);
            if (tid == 0) {
                mstat[((size_t)b * NT + tile) * 12 + g] = mv;
                sstat[((size_t)b * NT + tile) * 12 + g] = e;
            }
        }
    }
}

// ---------------------------------------------------------------------------
// k_ysum: combines 17-tile stats -> softmax p = exp(a1-m)/S, mix2 in LDS,
// then yp[k][b][h][c] = sum_{n in chunk} a2[h][n] * x[b][n][c].
// x pass 2. grid (8, 64), block 384 (6 waves): waves 0-2 rows [0,64),
// waves 3-5 rows [64,nn); partial accumulators combined through LDS.
// ---------------------------------------------------------------------------
#define FMA4(d, s, xv) { d.x += (s) * xv.x; d.y += (s) * xv.y; d.z += (s) * xv.z; d.w += (s) * xv.w; }
__global__ __launch_bounds__(384) void k_ysum(const float* __restrict__ x,
                                              const float* __restrict__ sc,
                                              const float* __restrict__ mstat,
                                              const float* __restrict__ sstat,
                                              const float* __restrict__ w2W,
                                              const float* __restrict__ w2b,
                                              float* __restrict__ yp) {
    __shared__ float as_[129 * 12];
    __shared__ float4 redv[192 * 12];     // 36 KB partial-acc combine buffer
    __shared__ float w2s[144], w2bs[12], msh[12], ish[12];
    int k = blockIdx.x, b = blockIdx.y, tid = threadIdx.x;
    int nlo = k * 128, nn = (k == 7) ? 129 : 128;
    if (tid < 144) w2s[tid] = w2W[tid];
    if (tid < 12) {
        w2bs[tid] = w2b[tid];
        float m = -3e38f, mv[NT];
        #pragma unroll
        for (int kk = 0; kk < NT; ++kk) {
            mv[kk] = mstat[((size_t)b * NT + kk) * 12 + tid];
            m = fmaxf(m, mv[kk]);
        }
        float S = 0.f;
        #pragma unroll
        for (int kk = 0; kk < NT; ++kk)
            S += sstat[((size_t)b * NT + kk) * 12 + tid] * __expf(mv[kk] - m);
        msh[tid] = m; ish[tid] = 1.f / S;
    }
    __syncthreads();
    if (tid < nn) {
        int n = nlo + tid;
        const float* sp = sc + ((size_t)b * N + n) * 12;
        float4 s0 = *(const float4*)(sp);
        float4 s1 = *(const float4*)(sp + 4);
        float4 s2 = *(const float4*)(sp + 8);
        float p[12];
        p[0]  = __expf(s0.x - msh[0])  * ish[0];
        p[1]  = __expf(s0.y - msh[1])  * ish[1];
        p[2]  = __expf(s0.z - msh[2])  * ish[2];
        p[3]  = __expf(s0.w - msh[3])  * ish[3];
        p[4]  = __expf(s1.x - msh[4])  * ish[4];
        p[5]  = __expf(s1.y - msh[5])  * ish[5];
        p[6]  = __expf(s1.z - msh[6])  * ish[6];
        p[7]  = __expf(s1.w - msh[7])  * ish[7];
        p[8]  = __expf(s2.x - msh[8])  * ish[8];
        p[9]  = __expf(s2.y - msh[9])  * ish[9];
        p[10] = __expf(s2.z - msh[10]) * ish[10];
        p[11] = __expf(s2.w - msh[11]) * ish[11];
        #pragma unroll
        for (int g = 0; g < 12; ++g) {
            float a = p[g] + w2bs[g];
            #pragma unroll
            for (int h = 0; h < 12; ++h) a += w2s[g * 12 + h] * p[h];
            as_[tid * 12 + g] = a;
        }
    }
    __syncthreads();
    int grp = tid / 192, t = tid - grp * 192;
    int n0   = grp ? 64 : 0;
    int nend = grp ? nn : 64;
    const float* xb = x + ((size_t)b * N + nlo) * C + t * 4;
    float4 acc[12] = {};
    int n = n0;
    for (; n + 4 <= nend; n += 4) {
        float4 xv[4];
        #pragma unroll
        for (int u = 0; u < 4; ++u)
            xv[u] = *(const float4*)(xb + (size_t)(n + u) * C);
        #pragma unroll
        for (int u = 0; u < 4; ++u) {
            const float4* ar = (const float4*)(as_ + (n + u) * 12);
            float4 a0 = ar[0], a1 = ar[1], a2 = ar[2];
            FMA4(acc[0], a0.x, xv[u]); FMA4(acc[1], a0.y, xv[u]); FMA4(acc[2], a0.z, xv[u]); FMA4(acc[3], a0.w, xv[u]);
            FMA4(acc[4], a1.x, xv[u]); FMA4(acc[5], a1.y, xv[u]); FMA4(acc[6], a1.z, xv[u]); FMA4(acc[7], a1.w, xv[u]);
            FMA4(acc[8], a2.x, xv[u]); FMA4(acc[9], a2.y, xv[u]); FMA4(acc[10], a2.z, xv[u]); FMA4(acc[11], a2.w, xv[u]);
        }
    }
    for (; n < nend; ++n) {
        float4 xv = *(const float4*)(xb + (size_t)n * C);
        const float4* ar = (const float4*)(as_ + n * 12);
        float4 a0 = ar[0], a1 = ar[1], a2 = ar[2];
        FMA4(acc[0], a0.x, xv); FMA4(acc[1], a0.y, xv); FMA4(acc[2], a0.z, xv); FMA4(acc[3], a0.w, xv);
        FMA4(acc[4], a1.x, xv); FMA4(acc[5], a1.y, xv); FMA4(acc[6], a1.z, xv); FMA4(acc[7], a1.w, xv);
        FMA4(acc[8], a2.x, xv); FMA4(acc[9], a2.y, xv); FMA4(acc[10], a2.z, xv); FMA4(acc[11], a2.w, xv);
    }
    if (grp == 1) {
        #pragma unroll
        for (int h = 0; h < 12; ++h) redv[t * 12 + h] = acc[h];
    }
    __syncthreads();
    if (grp == 0) {
        #pragma unroll
        for (int h = 0; h < 12; ++h) {
            float4 rv = redv[t * 12 + h];
            acc[h].x += rv.x; acc[h].y += rv.y; acc[h].z += rv.z; acc[h].w += rv.w;
        }
        #pragma unroll
        for (int h = 0; h < 12; ++h)
            *(float4*)(yp + (((size_t)k * B + b) * H + h) * C + t * 4) = acc[h];
    }
}

// ---------------------------------------------------------------------------
// k_zproj: ybar = sum_k yp[k]; z[b][c] = ybar[b,h(c),:] . vW[c,:] + vb[c]*sv,
// sv = 1 + rowsum(w2W)[h] + N*w2b[h] (softmax rows sum to 1 -> closed form).
// grid (16 btiles, 12 heads), block 256.
// ---------------------------------------------------------------------------
__global__ __launch_bounds__(256) void k_zproj(const float* __restrict__ yp,
                                               const float* __restrict__ vW,
                                               const float* __restrict__ vb,
                                               const float* __restrict__ w2W,
                                               const float* __restrict__ w2b,
                                               float* __restrict__ z) {
    __shared__ float ys[4 * C];
    int bt = blockIdx.x, h = blockIdx.y, tid = threadIdx.x;
    for (int i = tid; i < 768; i += 256) {   // 4 rows x 192 float4
        int bl = i / 192, c4 = i % 192;
        int b = bt * 4 + bl;
        float4 s = make_float4(0.f, 0.f, 0.f, 0.f);
        #pragma unroll
        for (int k = 0; k < 8; ++k) {
            float4 v = ((const float4*)(yp + (((size_t)k * B + b) * H + h) * C))[c4];
            s.x += v.x; s.y += v.y; s.z += v.z; s.w += v.w;
        }
        ((float4*)ys)[i] = s;
    }
    __syncthreads();
    float sv = 1.f + 1025.f * w2b[h];
    #pragma unroll
    for (int j = 0; j < 12; ++j) sv += w2W[h * 12 + j];
    int w = tid >> 6, lane = tid & 63;
    int b = bt * 4 + w;
    const float* yrow = &ys[w * C];
    for (int cl = 0; cl < 64; ++cl) {
        int c = h * 64 + cl;
        const float4* wr = (const float4*)(vW + (size_t)c * C + lane * 12);
        const float4* yr = (const float4*)(yrow + lane * 12);
        float acc = 0.f;
        #pragma unroll
        for (int s = 0; s < 3; ++s) {
            float4 a = wr[s], v = yr[s];
            acc += a.x * v.x + a.y * v.y + a.z * v.z + a.w * v.w;
        }
        acc = wave_reduce_add(acc);
        if (lane == 0) z[b * C + c] = acc + vb[c] * sv;
    }
}

// ---------------------------------------------------------------------------
// k_out: out[b][c] = z[b,:] . projW[c,:] + projb[c]
// grid (16 btiles, 48 ctiles of 16), block 256.
// ---------------------------------------------------------------------------
__global__ __launch_bounds__(256) void k_out(const float* __restrict__ z,
                                             const float* __restrict__ pW,
                                             const float* __restrict__ pb,
                                             float* __restrict__ out) {
    __shared__ float zs[4 * C];
    int bt = blockIdx.x, ct = blockIdx.y, tid = threadIdx.x;
    for (int i = tid; i < 768; i += 256)
        ((float4*)zs)[i] = ((const float4*)(z + (size_t)bt * 4 * C))[i];
    __syncthreads();
    int w = tid >> 6, lane = tid & 63;
    int b = bt * 4 + w;
    for (int cl = 0; cl < 16; ++cl) {
        int c = ct * 16 + cl;
        const float4* wr = (const float4*)(pW + (size_t)c * C + lane * 12);
        const float4* zr = (const float4*)(zs + w * C + lane * 12);
        float acc = 0.f;
        #pragma unroll
        for (int s = 0; s < 3; ++s) {
            float4 a = wr[s], v = zr[s];
            acc += a.x * v.x + a.y * v.y + a.z * v.z + a.w * v.w;
        }
        acc = wave_reduce_add(acc);
        if (lane == 0) out[b * C + c] = acc + pb[c];
    }
}

extern "C" void kernel_launch(void* const* d_in, const int* in_sizes, int n_in,
                              void* d_out, int out_size, void* d_ws, size_t ws_size,
                              hipStream_t stream) {
    const float* x    = (const float*)d_in[0];
    const float* qW   = (const float*)d_in[1];
    const float* qb   = (const float*)d_in[2];
    const float* kW   = (const float*)d_in[3];
    const float* kb   = (const float*)d_in[4];
    const float* vW   = (const float*)d_in[5];
    const float* vb   = (const float*)d_in[6];
    const float* w1W  = (const float*)d_in[7];
    const float* w1b  = (const float*)d_in[8];
    const float* w2W  = (const float*)d_in[9];
    const float* w2b  = (const float*)d_in[10];
    const float* pW   = (const float*)d_in[11];
    const float* pb   = (const float*)d_in[12];
    float* out = (float*)d_out;

    float* ws    = (float*)d_ws;
    float* qk    = ws + 0;        // 64*12*768  = 589824
    float* qkb   = ws + 589824;   // 768
    float* q     = ws + 590592;   // 49152
    float* sc    = ws + 639744;   // 64*1025*12 = 787200 (a1, [b][n][h] layout)
    float* yp    = ws + 1426944;  // 8*64*12*768 = 4718592
    float* z     = ws + 6145536;  // 49152
    float* mstat = ws + 6194688;  // 64*17*12 = 13056
    float* sstat = ws + 6207744;  // 13056
    // total 6220800 floats = 24.9 MB

    k_qproj <<<dim3(16, 48), 256, 0, stream>>>(x, qW, qb, q);
    k_qk    <<<dim3(16, 12), 256, 0, stream>>>(q, kW, kb, qk, qkb);
    k_scores<<<dim3(17, 64), 256, 0, stream>>>(x, qk, qkb, w1W, w1b, sc, mstat, sstat);
    k_ysum  <<<dim3(8, 64), 384, 0, stream>>>(x, sc, mstat, sstat, w2W, w2b, yp);
    k_zproj <<<dim3(16, 12), 256, 0, stream>>>(yp, vW, vb, w2W, w2b, z);
    k_out   <<<dim3(16, 48), 256, 0, stream>>>(z, pW, pb, out);
}